// Round 8
// baseline (215.743 us; speedup 1.0000x reference)
//
#include <hip/hip_runtime.h>

#define NN 100000
#define NE 1600000
#define NPB 128                       // nodes per coarse bucket (node>>7)
#define NBUCK ((NN + NPB - 1) / NPB)  // 782
#define NSB 512                       // hist chunks
#define ESB (NE / NSB)                // 3125 edges per hist chunk
#define SCHUNK 2                      // hist chunks per scatter block
#define SCATB (NSB / SCHUNK)          // 256 scatter blocks
#define ESCB (ESB * SCHUNK)           // 6250 edges per scatter block
#define PCAP 3072                     // LDS staging cap in place_deg (bucket avg ~2046)
#define BPAD (NPB * 7)                // 896 pad-slack slots per bucket
#define GEMMB ((NN + 63) / 64)        // 1563 gemm blocks

typedef __bf16 v8bf __attribute__((ext_vector_type(8)));
typedef float  v4f  __attribute__((ext_vector_type(4)));

union Frag { v8bf v; uint4 u; unsigned short s[8]; };

// fp32 -> bf16 (round-to-nearest-even), returns low 16 bits
__device__ inline unsigned f2bf(float f) {
    unsigned u = __float_as_uint(f);
    return (u + 0x7fffu + ((u >> 16) & 1u)) >> 16;
}

// accumulate 8 packed bf16 channels (uint4) into a[0..7]
#define ACC8(u) do { \
    a[0] += __uint_as_float((u).x << 16); \
    a[1] += __uint_as_float((u).x & 0xffff0000u); \
    a[2] += __uint_as_float((u).y << 16); \
    a[3] += __uint_as_float((u).y & 0xffff0000u); \
    a[4] += __uint_as_float((u).z << 16); \
    a[5] += __uint_as_float((u).z & 0xffff0000u); \
    a[6] += __uint_as_float((u).w << 16); \
    a[7] += __uint_as_float((u).w & 0xffff0000u); \
} while (0)

// accumulate with per-edge scalar weight dj: a[c] += dj * unpack(u.c)
#define ACC8N(u, dj) do { \
    a[0] = fmaf((dj), __uint_as_float((u).x << 16),         a[0]); \
    a[1] = fmaf((dj), __uint_as_float((u).x & 0xffff0000u), a[1]); \
    a[2] = fmaf((dj), __uint_as_float((u).y << 16),         a[2]); \
    a[3] = fmaf((dj), __uint_as_float((u).y & 0xffff0000u), a[3]); \
    a[4] = fmaf((dj), __uint_as_float((u).z << 16),         a[4]); \
    a[5] = fmaf((dj), __uint_as_float((u).z & 0xffff0000u), a[5]); \
    a[6] = fmaf((dj), __uint_as_float((u).w << 16),         a[6]); \
    a[7] = fmaf((dj), __uint_as_float((u).w & 0xffff0000u), a[7]); \
} while (0)

// broadcast lane j within 8-lane group: src = (lane & 0x18) | j  (BitMode swizzle)
#define BCAST8(x, j) __builtin_amdgcn_ds_swizzle((x), 0x18 | ((j) << 5))

// ---------------- K1: hist (512 blocks) + wpack W2 (1) + gemm1 (1563) --------
// gemm1 is fully independent of the CSR chain: self-packs W1 per block, so it
// overlaps the histogram instead of serializing behind scatter.
__global__ void hist_wpack_gemm_kernel(const int* __restrict__ dst, int* __restrict__ histT,
                                       const float* __restrict__ W1, const float* __restrict__ W2,
                                       unsigned short* __restrict__ Wp2,
                                       const float* __restrict__ x,
                                       unsigned* __restrict__ outA) {
    __shared__ __align__(16) char smem[18944];
    int b = blockIdx.x, t = threadIdx.x;
    if (b < NSB) {                           // ---- histogram ----
        int* lhist = (int*)smem;
        for (int i = t; i < NBUCK; i += 256) lhist[i] = 0;
        __syncthreads();
        int start = b * ESB, end = start + ESB;
        int e = start + t;
        for (; e + 3 * 256 < end; e += 4 * 256) {
            int d0 = dst[e], d1 = dst[e + 256], d2 = dst[e + 512], d3 = dst[e + 768];
            atomicAdd(&lhist[d0 >> 7], 1);
            atomicAdd(&lhist[d1 >> 7], 1);
            atomicAdd(&lhist[d2 >> 7], 1);
            atomicAdd(&lhist[d3 >> 7], 1);
        }
        for (; e < end; e += 256)
            atomicAdd(&lhist[dst[e] >> 7], 1);
        __syncthreads();
        for (int i = t; i < NBUCK; i += 256)
            histT[i * NSB + b] = lhist[i];   // transposed: bucket-major
        return;
    }
    if (b == NSB) {                          // ---- wpack W2 -> global ----
        for (int idx = t; idx < 4096; idx += 256) {
            int j = idx & 7;
            int n = (idx >> 3) & 15;
            int f = idx >> 7;
            int q = f & 3;
            int s = (f >> 2) & 1;
            int c = f >> 3;
            int kk = 32 * s + 8 * q + j;
            Wp2[idx] = (unsigned short)f2bf(W2[kk * 64 + (16 * c + n)]);
        }
        return;
    }
    // ---- gemm1: fp32 x -> bf16 unscaled h1; row NN zeroed ----
    unsigned short (*xs)[80] = (unsigned short(*)[80])smem;      // 10240 B
    unsigned short* wpl = (unsigned short*)(smem + 10240);       // 8192 B
    int gb = b - NSB - 1;
    int node0 = gb * 64;
    #pragma unroll
    for (int i = 0; i < 4; ++i) {            // stage x tile (coalesced float4)
        int idx = i * 256 + t;
        int row = idx >> 4;
        int c4  = idx & 15;
        int gn  = node0 + row;
        int gr  = (gn < NN) ? gn : NN - 1;
        float4 f = *(const float4*)(x + gr * 64 + c4 * 4);
        unsigned lo = f2bf(f.x) | (f2bf(f.y) << 16);
        unsigned hi = f2bf(f.z) | (f2bf(f.w) << 16);
        *(uint2*)&xs[row][c4 * 4] = make_uint2(lo, hi);
    }
    for (int idx = t; idx < 4096; idx += 256) {  // self-pack W1 -> LDS
        int j = idx & 7;
        int n = (idx >> 3) & 15;
        int f = idx >> 7;
        int q = f & 3;
        int s = (f >> 2) & 1;
        int c = f >> 3;
        int kk = 32 * s + 8 * q + j;
        wpl[idx] = (unsigned short)f2bf(W1[kk * 64 + (16 * c + n)]);
    }
    __syncthreads();

    int lane = t & 63;
    int wv = t >> 6;
    int m = lane & 15, quad = lane >> 4;
    int nl = wv * 16 + m;

    Frag a[2];
    #pragma unroll
    for (int s = 0; s < 2; ++s)
        a[s].u = *(const uint4*)&xs[nl][s * 32 + quad * 8];
    Frag bf[8];
    #pragma unroll
    for (int cs = 0; cs < 8; ++cs)
        bf[cs].u = *(const uint4*)&wpl[((cs * 4 + quad) * 16 + m) * 8];

    v4f acc[4] = {};
    #pragma unroll
    for (int c = 0; c < 4; ++c) {
        acc[c] = __builtin_amdgcn_mfma_f32_16x16x32_bf16(a[0].v, bf[c * 2 + 0].v, acc[c], 0, 0, 0);
        acc[c] = __builtin_amdgcn_mfma_f32_16x16x32_bf16(a[1].v, bf[c * 2 + 1].v, acc[c], 0, 0, 0);
    }
    #pragma unroll
    for (int r = 0; r < 4; ++r) {
        int onode = node0 + wv * 16 + quad * 4 + r;
        #pragma unroll
        for (int c = 0; c < 4; ++c) {
            float v = acc[c][r];
            float p = __shfl_xor(v, 1);
            if (!(lane & 1)) {
                if (onode < NN)
                    outA[onode * 32 + c * 8 + (m >> 1)] = f2bf(v) | (f2bf(p) << 16);
                else if (onode == NN)
                    outA[onode * 32 + c * 8 + (m >> 1)] = 0u;   // zero row for padding
            }
        }
    }
}

// ---------------- K2: per-bucket scan of 512 chunk counts --------------------
// baseTT is CHUNK-MAJOR: baseTT[chunk * NBUCK + bucket].
__global__ void colscan_kernel(const int* __restrict__ histT, int* __restrict__ baseTT,
                               int* __restrict__ btot) {
    __shared__ int sd[256];
    int k = blockIdx.x, t = threadIdx.x;
    const int* col = histT + k * NSB;
    int a0 = col[2 * t], a1 = col[2 * t + 1];
    int my = a0 + a1;
    sd[t] = my;
    __syncthreads();
    #pragma unroll
    for (int off = 1; off < 256; off <<= 1) {
        int v = (t >= off) ? sd[t - off] : 0;
        __syncthreads();
        sd[t] += v;
        __syncthreads();
    }
    int excl = sd[t] - my;
    baseTT[(2 * t) * NBUCK + k]     = excl;
    baseTT[(2 * t + 1) * NBUCK + k] = excl + a0;
    if (t == 255) btot[k] = sd[255];
}

// ---------------- K3: 2-chunk bucket scatter ---------------------------------
__global__ void scatter_kernel(const int* __restrict__ src, const int* __restrict__ dst,
                               const int* __restrict__ baseTT, const int* __restrict__ btot,
                               int* __restrict__ pairs) {
    __shared__ int lcur[NBUCK];
    __shared__ int sd[256];
    int b = blockIdx.x, t = threadIdx.x;
    int base4 = t * 4;
    int d0 = (base4 + 0 < NBUCK) ? btot[base4 + 0] : 0;
    int d1 = (base4 + 1 < NBUCK) ? btot[base4 + 1] : 0;
    int d2 = (base4 + 2 < NBUCK) ? btot[base4 + 2] : 0;
    int d3 = (base4 + 3 < NBUCK) ? btot[base4 + 3] : 0;
    int my = d0 + d1 + d2 + d3;
    sd[t] = my;
    __syncthreads();
    #pragma unroll
    for (int off = 1; off < 256; off <<= 1) {
        int v = (t >= off) ? sd[t - off] : 0;
        __syncthreads();
        sd[t] += v;
        __syncthreads();
    }
    int excl = sd[t] - my;
    const int* bcol = baseTT + (b * SCHUNK) * NBUCK;   // contiguous column
    if (base4 + 0 < NBUCK) lcur[base4 + 0] = excl + bcol[base4 + 0];
    if (base4 + 1 < NBUCK) lcur[base4 + 1] = excl + d0 + bcol[base4 + 1];
    if (base4 + 2 < NBUCK) lcur[base4 + 2] = excl + d0 + d1 + bcol[base4 + 2];
    if (base4 + 3 < NBUCK) lcur[base4 + 3] = excl + d0 + d1 + d2 + bcol[base4 + 3];
    __syncthreads();
    int start = b * ESCB, end = start + ESCB;
    int e = start + t;
    for (; e + 3 * 256 < end; e += 4 * 256) {
        int dd0 = dst[e], dd1 = dst[e + 256], dd2 = dst[e + 512], dd3 = dst[e + 768];
        int ss0 = src[e], ss1 = src[e + 256], ss2 = src[e + 512], ss3 = src[e + 768];
        int p0 = atomicAdd(&lcur[dd0 >> 7], 1);
        int p1 = atomicAdd(&lcur[dd1 >> 7], 1);
        int p2 = atomicAdd(&lcur[dd2 >> 7], 1);
        int p3 = atomicAdd(&lcur[dd3 >> 7], 1);
        pairs[p0] = ((dd0 & 127) << 20) | ss0;
        pairs[p1] = ((dd1 & 127) << 20) | ss1;
        pairs[p2] = ((dd2 & 127) << 20) | ss2;
        pairs[p3] = ((dd3 & 127) << 20) | ss3;
    }
    for (; e < end; e += 256) {
        int d = dst[e];
        int pos = atomicAdd(&lcur[d >> 7], 1);
        pairs[pos] = ((d & 127) << 20) | src[e];
    }
}

// ---------------- K4: padded CSR placement + dinv + degree-rank perm ---------
// gperm[k*128 + rank] = node, ranks sorted by padded-degree (16-bin counting
// sort). Unused ranks point at node0 (valid; duplicate gather writes same value).
__global__ void place_deg_kernel(const int* __restrict__ btot,
                                 const int* __restrict__ pairs,
                                 int2* __restrict__ rs_pd, float* __restrict__ dinv,
                                 int* __restrict__ srt, int* __restrict__ gperm) {
    __shared__ int lp[PCAP];
    __shared__ int lcnt[NPB];
    __shared__ int loff[NPB];
    __shared__ int lpos[NPB];
    __shared__ int sd[256];
    __shared__ int bin[16];
    __shared__ int bs_s;
    int k = blockIdx.x, t = threadIdx.x;
    int node0 = k * NPB;
    int part = 0;
    for (int i = t; i < k; i += 256) part += btot[i];
    sd[t] = part;
    __syncthreads();
    #pragma unroll
    for (int off = 128; off; off >>= 1) {
        if (t < off) sd[t] += sd[t + off];
        __syncthreads();
    }
    if (t == 0) bs_s = sd[0];
    if (t < NPB) { lcnt[t] = 0; lpos[t] = 0; }
    if (k == 0 && t == 0) dinv[NN] = 0.f;   // dinv of the zero row (pads)
    __syncthreads();
    int bs = bs_s;
    int n = btot[k];
    int base = bs + k * BPAD;
    for (int pos = t; pos < n; pos += 256) {
        int p = pairs[bs + pos];
        if (pos < PCAP) lp[pos] = p;
        atomicAdd(&lcnt[p >> 20], 1);
    }
    __syncthreads();
    int my = (t < NPB) ? lcnt[t] : 0;
    int pd = (my + 7) & ~7;              // padded degree
    if (t < NPB) sd[t] = pd;
    __syncthreads();
    #pragma unroll
    for (int off = 1; off < NPB; off <<= 1) {
        int v = (t < NPB && t >= off) ? sd[t - off] : 0;
        __syncthreads();
        if (t < NPB) sd[t] += v;
        __syncthreads();
    }
    if (t < NPB) {
        int excl = sd[t] - pd;
        loff[t] = excl;
        int nd = node0 + t;
        if (nd < NN) {
            rs_pd[nd] = make_int2(base + excl, pd);
            dinv[nd] = rsqrtf((float)(my + 1));
            for (int kk = my; kk < pd; ++kk)
                srt[base + excl + kk] = NN;   // pad -> zero row
        }
    }
    // ---- degree-rank counting sort -> gperm ----
    if (t < NPB) gperm[node0 + t] = node0;   // default: valid duplicate
    if (t < 16) bin[t] = 0;
    __syncthreads();
    int nchv = min(pd >> 3, 15);
    if (t < NPB && node0 + t < NN) atomicAdd(&bin[nchv], 1);
    __syncthreads();
    if (t == 0) {
        int s = 0;
        #pragma unroll
        for (int i = 0; i < 16; ++i) { int c = bin[i]; bin[i] = s; s += c; }
    }
    __syncthreads();
    if (t < NPB && node0 + t < NN) {
        int r = atomicAdd(&bin[nchv], 1);
        gperm[node0 + r] = node0 + t;
    }
    __syncthreads();
    for (int pos = t; pos < n; pos += 256) {
        int p = (pos < PCAP) ? lp[pos] : pairs[bs + pos];
        int loc = p >> 20;
        int off = atomicAdd(&lpos[loc], 1);
        srt[base + loff[loc] + off] = p & 0xFFFFF;
    }
}

// ---------------- gather core A: prescaled rows, software-pipelined ----------
__device__ inline void gather8(const int2* __restrict__ rs_pd,
                               const int* __restrict__ srt,
                               const uint4* __restrict__ hb4,
                               int node, int q8, float a[8]) {
    int2 rp = rs_pd[node];
    uint4 u0 = hb4[node * 8 + q8];   // self-loop term
    a[0] = __uint_as_float(u0.x << 16);
    a[1] = __uint_as_float(u0.x & 0xffff0000u);
    a[2] = __uint_as_float(u0.y << 16);
    a[3] = __uint_as_float(u0.y & 0xffff0000u);
    a[4] = __uint_as_float(u0.z << 16);
    a[5] = __uint_as_float(u0.z & 0xffff0000u);
    a[6] = __uint_as_float(u0.w << 16);
    a[7] = __uint_as_float(u0.w & 0xffff0000u);
    int nch = rp.y >> 3;
    if (nch == 0) return;
    int base = rp.x + q8;
    int sc = srt[base];
    int i0 = BCAST8(sc, 0), i1 = BCAST8(sc, 1), i2 = BCAST8(sc, 2), i3 = BCAST8(sc, 3);
    int i4 = BCAST8(sc, 4), i5 = BCAST8(sc, 5), i6 = BCAST8(sc, 6), i7 = BCAST8(sc, 7);
    uint4 c0 = hb4[i0 * 8 + q8], c1 = hb4[i1 * 8 + q8];
    uint4 c2 = hb4[i2 * 8 + q8], c3 = hb4[i3 * 8 + q8];
    uint4 c4 = hb4[i4 * 8 + q8], c5 = hb4[i5 * 8 + q8];
    uint4 c6 = hb4[i6 * 8 + q8], c7 = hb4[i7 * 8 + q8];
    int sn = (nch > 1) ? srt[base + 8] : 0;
    #pragma unroll 2
    for (int i = 1; i < nch; ++i) {
        int j0 = BCAST8(sn, 0), j1 = BCAST8(sn, 1), j2 = BCAST8(sn, 2), j3 = BCAST8(sn, 3);
        int j4 = BCAST8(sn, 4), j5 = BCAST8(sn, 5), j6 = BCAST8(sn, 6), j7 = BCAST8(sn, 7);
        uint4 n0 = hb4[j0 * 8 + q8], n1 = hb4[j1 * 8 + q8];
        uint4 n2 = hb4[j2 * 8 + q8], n3 = hb4[j3 * 8 + q8];
        uint4 n4 = hb4[j4 * 8 + q8], n5 = hb4[j5 * 8 + q8];
        uint4 n6 = hb4[j6 * 8 + q8], n7 = hb4[j7 * 8 + q8];
        int sf = (i + 1 < nch) ? srt[base + (i + 1) * 8] : 0;
        ACC8(c0); ACC8(c1); ACC8(c2); ACC8(c3);
        ACC8(c4); ACC8(c5); ACC8(c6); ACC8(c7);
        c0 = n0; c1 = n1; c2 = n2; c3 = n3;
        c4 = n4; c5 = n5; c6 = n6; c7 = n7;
        sn = sf;
    }
    ACC8(c0); ACC8(c1); ACC8(c2); ACC8(c3);
    ACC8(c4); ACC8(c5); ACC8(c6); ACC8(c7);
}

// ---------------- gather core B: unscaled rows + dinv[src], pipelined --------
__device__ inline void gather8n(const int2* __restrict__ rs_pd,
                                const int* __restrict__ srt,
                                const uint4* __restrict__ hb4,
                                const float* __restrict__ dinv,
                                int node, int q8, float di, float a[8]) {
    int2 rp = rs_pd[node];
    uint4 u0 = hb4[node * 8 + q8];   // self-loop term (unscaled)
    a[0] = di * __uint_as_float(u0.x << 16);
    a[1] = di * __uint_as_float(u0.x & 0xffff0000u);
    a[2] = di * __uint_as_float(u0.y << 16);
    a[3] = di * __uint_as_float(u0.y & 0xffff0000u);
    a[4] = di * __uint_as_float(u0.z << 16);
    a[5] = di * __uint_as_float(u0.z & 0xffff0000u);
    a[6] = di * __uint_as_float(u0.w << 16);
    a[7] = di * __uint_as_float(u0.w & 0xffff0000u);
    int nch = rp.y >> 3;
    if (nch == 0) return;
    int base = rp.x + q8;
    int sc = srt[base];
    float dc = dinv[sc];             // dinv[NN] = 0 covers pads
    int i0 = BCAST8(sc, 0), i1 = BCAST8(sc, 1), i2 = BCAST8(sc, 2), i3 = BCAST8(sc, 3);
    int i4 = BCAST8(sc, 4), i5 = BCAST8(sc, 5), i6 = BCAST8(sc, 6), i7 = BCAST8(sc, 7);
    uint4 c0 = hb4[i0 * 8 + q8], c1 = hb4[i1 * 8 + q8];
    uint4 c2 = hb4[i2 * 8 + q8], c3 = hb4[i3 * 8 + q8];
    uint4 c4 = hb4[i4 * 8 + q8], c5 = hb4[i5 * 8 + q8];
    uint4 c6 = hb4[i6 * 8 + q8], c7 = hb4[i7 * 8 + q8];
    int sn = 0; float dn = 0.f;
    if (nch > 1) { sn = srt[base + 8]; dn = dinv[sn]; }
    #pragma unroll 2
    for (int i = 1; i < nch; ++i) {
        int j0 = BCAST8(sn, 0), j1 = BCAST8(sn, 1), j2 = BCAST8(sn, 2), j3 = BCAST8(sn, 3);
        int j4 = BCAST8(sn, 4), j5 = BCAST8(sn, 5), j6 = BCAST8(sn, 6), j7 = BCAST8(sn, 7);
        uint4 n0 = hb4[j0 * 8 + q8], n1 = hb4[j1 * 8 + q8];
        uint4 n2 = hb4[j2 * 8 + q8], n3 = hb4[j3 * 8 + q8];
        uint4 n4 = hb4[j4 * 8 + q8], n5 = hb4[j5 * 8 + q8];
        uint4 n6 = hb4[j6 * 8 + q8], n7 = hb4[j7 * 8 + q8];
        int sf = 0; float df = 0.f;
        if (i + 1 < nch) { sf = srt[base + (i + 1) * 8]; df = dinv[sf]; }
        int dci = __float_as_int(dc);
        float w0 = __int_as_float(BCAST8(dci, 0));
        float w1 = __int_as_float(BCAST8(dci, 1));
        float w2 = __int_as_float(BCAST8(dci, 2));
        float w3 = __int_as_float(BCAST8(dci, 3));
        float w4 = __int_as_float(BCAST8(dci, 4));
        float w5 = __int_as_float(BCAST8(dci, 5));
        float w6 = __int_as_float(BCAST8(dci, 6));
        float w7 = __int_as_float(BCAST8(dci, 7));
        ACC8N(c0, w0); ACC8N(c1, w1); ACC8N(c2, w2); ACC8N(c3, w3);
        ACC8N(c4, w4); ACC8N(c5, w5); ACC8N(c6, w6); ACC8N(c7, w7);
        c0 = n0; c1 = n1; c2 = n2; c3 = n3;
        c4 = n4; c5 = n5; c6 = n6; c7 = n7;
        dc = dn; sn = sf; dn = df;
    }
    int dci = __float_as_int(dc);
    float w0 = __int_as_float(BCAST8(dci, 0));
    float w1 = __int_as_float(BCAST8(dci, 1));
    float w2 = __int_as_float(BCAST8(dci, 2));
    float w3 = __int_as_float(BCAST8(dci, 3));
    float w4 = __int_as_float(BCAST8(dci, 4));
    float w5 = __int_as_float(BCAST8(dci, 5));
    float w6 = __int_as_float(BCAST8(dci, 6));
    float w7 = __int_as_float(BCAST8(dci, 7));
    ACC8N(c0, w0); ACC8N(c1, w1); ACC8N(c2, w2); ACC8N(c3, w3);
    ACC8N(c4, w4); ACC8N(c5, w5); ACC8N(c6, w6); ACC8N(c7, w7);
}

// ---------------- K5: bucket-aligned agg1 (degree-rank order) + gemm2 --------
// 782 blocks x 512 threads; block = bucket (128 nodes). Wave w gathers ranks
// w*16+pass*8+g (consecutive -> equal degrees -> no masked-lane waste); result
// lands at the node's true local row, MFMA phase reads natural order.
__global__ void agg1_gemm2_kernel(const int2* __restrict__ rs_pd,
                                  const int* __restrict__ srt,
                                  const uint4* __restrict__ hb4,   // bufA (unscaled)
                                  const float* __restrict__ dinv,
                                  const float* __restrict__ b1,
                                  const unsigned short* __restrict__ Wp2,
                                  const int* __restrict__ gperm,
                                  unsigned* __restrict__ out /* bufC bf16 rows */) {
    __shared__ unsigned short hsl[128][80];   // 20480 B
    int t = threadIdx.x;
    int lane = t & 63, wv = t >> 6;           // wv 0..7
    int node0 = blockIdx.x * NPB;
    int q8 = lane & 7, g = lane >> 3;
    float4 bb0 = *(const float4*)(b1 + q8 * 8);
    float4 bb1 = *(const float4*)(b1 + q8 * 8 + 4);

    #pragma unroll
    for (int pass = 0; pass < 2; ++pass) {
        int rank = wv * 16 + pass * 8 + g;
        int node = gperm[node0 + rank];       // always valid (< NN)
        float di = dinv[node];
        float a[8];
        gather8n(rs_pd, srt, hb4, dinv, node, q8, di, a);
        a[0] = fmaxf(fmaf(di, a[0], bb0.x), 0.f);
        a[1] = fmaxf(fmaf(di, a[1], bb0.y), 0.f);
        a[2] = fmaxf(fmaf(di, a[2], bb0.z), 0.f);
        a[3] = fmaxf(fmaf(di, a[3], bb0.w), 0.f);
        a[4] = fmaxf(fmaf(di, a[4], bb1.x), 0.f);
        a[5] = fmaxf(fmaf(di, a[5], bb1.y), 0.f);
        a[6] = fmaxf(fmaf(di, a[6], bb1.z), 0.f);
        a[7] = fmaxf(fmaf(di, a[7], bb1.w), 0.f);
        uint4 pk;
        pk.x = f2bf(a[0]) | (f2bf(a[1]) << 16);
        pk.y = f2bf(a[2]) | (f2bf(a[3]) << 16);
        pk.z = f2bf(a[4]) | (f2bf(a[5]) << 16);
        pk.w = f2bf(a[6]) | (f2bf(a[7]) << 16);
        *(uint4*)&hsl[node - node0][q8 * 8] = pk;   // true local row
    }
    __syncthreads();

    int m = lane & 15, quad = lane >> 4;
    Frag b[8];
    #pragma unroll
    for (int cs = 0; cs < 8; ++cs)
        b[cs].u = *(const uint4*)(Wp2 + ((cs * 4 + quad) * 16 + m) * 8);
    Frag a2[2];
    #pragma unroll
    for (int s = 0; s < 2; ++s)
        a2[s].u = *(const uint4*)&hsl[wv * 16 + m][s * 32 + quad * 8];

    v4f acc[4] = {};
    #pragma unroll
    for (int c = 0; c < 4; ++c) {
        acc[c] = __builtin_amdgcn_mfma_f32_16x16x32_bf16(a2[0].v, b[c * 2 + 0].v, acc[c], 0, 0, 0);
        acc[c] = __builtin_amdgcn_mfma_f32_16x16x32_bf16(a2[1].v, b[c * 2 + 1].v, acc[c], 0, 0, 0);
    }
    #pragma unroll
    for (int r = 0; r < 4; ++r) {
        int onode = node0 + wv * 16 + quad * 4 + r;
        float di = dinv[(onode < NN) ? onode : NN - 1];
        #pragma unroll
        for (int c = 0; c < 4; ++c) {
            float v = acc[c][r] * di;
            float p = __shfl_xor(v, 1);
            if (!(lane & 1)) {
                if (onode < NN)
                    out[onode * 32 + c * 8 + (m >> 1)] = f2bf(v) | (f2bf(p) << 16);
                else if (onode == NN)
                    out[onode * 32 + c * 8 + (m >> 1)] = 0u;   // zero row for padding
            }
        }
    }
}

// ---------------- K6: bucket-aligned agg2 (degree-rank) + FC + log_softmax ---
__global__ void aggregate2_final_kernel(const int2* __restrict__ rs_pd,
                                        const int* __restrict__ srt,
                                        const uint4* __restrict__ hb4,  // bufC
                                        const float* __restrict__ dinv,
                                        const float* __restrict__ b2,
                                        const float* __restrict__ Wfc,
                                        const float* __restrict__ bfc,
                                        const int* __restrict__ gperm,
                                        float* __restrict__ out) {
    __shared__ float Ws[64][16];     // 4 KB
    __shared__ float hs[128][68];    // 34.8 KB
    int t = threadIdx.x;
    #pragma unroll
    for (int k = 0; k < 2; ++k)
        ((float*)Ws)[k * 512 + t] = Wfc[k * 512 + t];

    int lane = t & 63, wv = t >> 6;
    int node0 = blockIdx.x * NPB;
    int q8 = lane & 7, g = lane >> 3;
    float4 bb0 = *(const float4*)(b2 + q8 * 8);
    float4 bb1 = *(const float4*)(b2 + q8 * 8 + 4);

    #pragma unroll
    for (int pass = 0; pass < 2; ++pass) {
        int rank = wv * 16 + pass * 8 + g;
        int node = gperm[node0 + rank];
        float a[8];
        gather8(rs_pd, srt, hb4, node, q8, a);
        float di = dinv[node];
        float4 r0, r1;
        r0.x = fmaxf(fmaf(di, a[0], bb0.x), 0.f);
        r0.y = fmaxf(fmaf(di, a[1], bb0.y), 0.f);
        r0.z = fmaxf(fmaf(di, a[2], bb0.z), 0.f);
        r0.w = fmaxf(fmaf(di, a[3], bb0.w), 0.f);
        r1.x = fmaxf(fmaf(di, a[4], bb1.x), 0.f);
        r1.y = fmaxf(fmaf(di, a[5], bb1.y), 0.f);
        r1.z = fmaxf(fmaf(di, a[6], bb1.z), 0.f);
        r1.w = fmaxf(fmaf(di, a[7], bb1.w), 0.f);
        int nl = node - node0;
        *(float4*)&hs[nl][q8 * 8]     = r0;
        *(float4*)&hs[nl][q8 * 8 + 4] = r1;
    }
    __syncthreads();

    #pragma unroll
    for (int it = 0; it < 4; ++it) {
        int idx = it * 512 + t;
        int n2 = idx >> 4;
        int c  = idx & 15;
        int node = node0 + n2;
        float acc = bfc[c];
        #pragma unroll
        for (int k = 0; k < 64; ++k)
            acc = fmaf(hs[n2][k], Ws[k][c], acc);
        float mx = acc;
        #pragma unroll
        for (int off = 8; off; off >>= 1)
            mx = fmaxf(mx, __shfl_xor(mx, off, 16));
        float ex = __expf(acc - mx);
        float s = ex;
        #pragma unroll
        for (int off = 8; off; off >>= 1)
            s += __shfl_xor(s, off, 16);
        if (node < NN)
            out[node * 16 + c] = acc - mx - __logf(s);
    }
}

extern "C" void kernel_launch(void* const* d_in, const int* in_sizes, int n_in,
                              void* d_out, int out_size, void* d_ws, size_t ws_size,
                              hipStream_t stream) {
    const float* x   = (const float*)d_in[0];
    const int*   ei  = (const int*)d_in[1];     // [2, E] int32
    const float* W1  = (const float*)d_in[2];
    const float* b1  = (const float*)d_in[3];
    const float* W2  = (const float*)d_in[4];
    const float* b2  = (const float*)d_in[5];
    const float* Wfc = (const float*)d_in[6];
    const float* bfc = (const float*)d_in[7];
    float* out = (float*)d_out;

    char* ws = (char*)d_ws;
    int2*     rs_pd  = (int2*)(ws + 0);             //  800,000 B
    float*    dinv   = (float*)(ws + 800000);       //  (NN+1)*4 -> ends 1200004
    int*      btot   = (int*)(ws + 1200128);        //  3128 B
    int*      histT  = (int*)(ws + 1203328);        //  1,601,536 -> ends 2804864
    int*      baseTT = (int*)(ws + 2804864);        //  1,601,536 -> ends 4406400 (chunk-major)
    int*      srt    = (int*)(ws + 4406400);        //  9,202,688 -> ends 13609088
    unsigned* bufA   = (unsigned*)(ws + 13609088);  // 12,800,128 -> ends 26409216
    int*      pairs  = (int*)(ws + 26409216);       //  6.4 MB (dead after K4)
    unsigned* bufC   = (unsigned*)(ws + 26409216);  // 12,800,128, overlays pairs -> ends 39209344
    unsigned short* Wp2 = (unsigned short*)(ws + 39209344);  // 8 KB -> ends 39217536
    int*      gperm  = (int*)(ws + 39217536);       // NBUCK*128*4 = 400,384 -> ends 39617920

    const int* src = ei;        // edge_index[0]
    const int* dst = ei + NE;   // edge_index[1]

    // K1: histogram + wpack W2 + layer-1 GEMM (independent halves, one dispatch)
    hist_wpack_gemm_kernel<<<NSB + 1 + GEMMB, 256, 0, stream>>>(dst, histT, W1, W2,
                                                                Wp2, x, bufA);
    // K2: per-bucket column scan (chunk-major output)
    colscan_kernel<<<NBUCK, 256, 0, stream>>>(histT, baseTT, btot);
    // K3: bucket scatter
    scatter_kernel<<<SCATB, 256, 0, stream>>>(src, dst, baseTT, btot, pairs);
    // K4: padded CSR placement + deg/dinv + degree-rank perm
    place_deg_kernel<<<NBUCK, 256, 0, stream>>>(btot, pairs, rs_pd, dinv, srt, gperm);
    // K5: layer-1 aggregate (degree-rank order) + layer-2 gemm
    agg1_gemm2_kernel<<<NBUCK, 512, 0, stream>>>(rs_pd, srt,
        (const uint4*)bufA, dinv, b1, Wp2, gperm, bufC);
    // K6: layer-2 aggregate (degree-rank order) + FC + log_softmax
    aggregate2_final_kernel<<<NBUCK, 512, 0, stream>>>(rs_pd, srt,
        (const uint4*)bufC, dinv, b2, Wfc, bfc, gperm, out);
}

// Round 9
// 201.994 us; speedup vs baseline: 1.0681x; 1.0681x over previous
//
#include <hip/hip_runtime.h>

#define NN 100000
#define NE 1600000
#define NPB 128                       // nodes per coarse bucket (node>>7)
#define NBUCK ((NN + NPB - 1) / NPB)  // 782
#define NSB 512                       // hist chunks
#define ESB (NE / NSB)                // 3125 edges per hist chunk
#define SCHUNK 2                      // hist chunks per scatter block
#define SCATB (NSB / SCHUNK)          // 256 scatter blocks
#define ESCB (ESB * SCHUNK)           // 6250 edges per scatter block
#define PCAP 3072                     // LDS staging cap in place_deg (bucket avg ~2046)
#define BPAD (NPB * 7)                // 896 pad-slack slots per bucket
#define GEMMB ((NN + 63) / 64)        // 1563 gemm blocks

typedef __bf16 v8bf __attribute__((ext_vector_type(8)));
typedef float  v4f  __attribute__((ext_vector_type(4)));

union Frag { v8bf v; uint4 u; unsigned short s[8]; };

// fp32 -> bf16 (round-to-nearest-even), returns low 16 bits
__device__ inline unsigned f2bf(float f) {
    unsigned u = __float_as_uint(f);
    return (u + 0x7fffu + ((u >> 16) & 1u)) >> 16;
}

// accumulate 8 packed bf16 channels (uint4) into a[0..7]
#define ACC8(u) do { \
    a[0] += __uint_as_float((u).x << 16); \
    a[1] += __uint_as_float((u).x & 0xffff0000u); \
    a[2] += __uint_as_float((u).y << 16); \
    a[3] += __uint_as_float((u).y & 0xffff0000u); \
    a[4] += __uint_as_float((u).z << 16); \
    a[5] += __uint_as_float((u).z & 0xffff0000u); \
    a[6] += __uint_as_float((u).w << 16); \
    a[7] += __uint_as_float((u).w & 0xffff0000u); \
} while (0)

// accumulate with per-edge scalar weight dj: a[c] += dj * unpack(u.c)
#define ACC8N(u, dj) do { \
    a[0] = fmaf((dj), __uint_as_float((u).x << 16),         a[0]); \
    a[1] = fmaf((dj), __uint_as_float((u).x & 0xffff0000u), a[1]); \
    a[2] = fmaf((dj), __uint_as_float((u).y << 16),         a[2]); \
    a[3] = fmaf((dj), __uint_as_float((u).y & 0xffff0000u), a[3]); \
    a[4] = fmaf((dj), __uint_as_float((u).z << 16),         a[4]); \
    a[5] = fmaf((dj), __uint_as_float((u).z & 0xffff0000u), a[5]); \
    a[6] = fmaf((dj), __uint_as_float((u).w << 16),         a[6]); \
    a[7] = fmaf((dj), __uint_as_float((u).w & 0xffff0000u), a[7]); \
} while (0)

// broadcast lane j within 8-lane group: src = (lane & 0x18) | j  (BitMode swizzle)
#define BCAST8(x, j) __builtin_amdgcn_ds_swizzle((x), 0x18 | ((j) << 5))

// ---------------- K1: hist (512 blocks) + wpack W2 (1) + gemm1 (1563) --------
// gemm1 is fully independent of the CSR chain: self-packs W1 per block, so it
// overlaps the histogram instead of serializing behind scatter.
__global__ void hist_wpack_gemm_kernel(const int* __restrict__ dst, int* __restrict__ histT,
                                       const float* __restrict__ W1, const float* __restrict__ W2,
                                       unsigned short* __restrict__ Wp2,
                                       const float* __restrict__ x,
                                       unsigned* __restrict__ outA) {
    __shared__ __align__(16) char smem[18944];
    int b = blockIdx.x, t = threadIdx.x;
    if (b < NSB) {                           // ---- histogram ----
        int* lhist = (int*)smem;
        for (int i = t; i < NBUCK; i += 256) lhist[i] = 0;
        __syncthreads();
        int start = b * ESB, end = start + ESB;
        int e = start + t;
        for (; e + 3 * 256 < end; e += 4 * 256) {
            int d0 = dst[e], d1 = dst[e + 256], d2 = dst[e + 512], d3 = dst[e + 768];
            atomicAdd(&lhist[d0 >> 7], 1);
            atomicAdd(&lhist[d1 >> 7], 1);
            atomicAdd(&lhist[d2 >> 7], 1);
            atomicAdd(&lhist[d3 >> 7], 1);
        }
        for (; e < end; e += 256)
            atomicAdd(&lhist[dst[e] >> 7], 1);
        __syncthreads();
        for (int i = t; i < NBUCK; i += 256)
            histT[i * NSB + b] = lhist[i];   // transposed: bucket-major
        return;
    }
    if (b == NSB) {                          // ---- wpack W2 -> global ----
        for (int idx = t; idx < 4096; idx += 256) {
            int j = idx & 7;
            int n = (idx >> 3) & 15;
            int f = idx >> 7;
            int q = f & 3;
            int s = (f >> 2) & 1;
            int c = f >> 3;
            int kk = 32 * s + 8 * q + j;
            Wp2[idx] = (unsigned short)f2bf(W2[kk * 64 + (16 * c + n)]);
        }
        return;
    }
    // ---- gemm1: fp32 x -> bf16 unscaled h1; row NN zeroed ----
    unsigned short (*xs)[80] = (unsigned short(*)[80])smem;      // 10240 B
    unsigned short* wpl = (unsigned short*)(smem + 10240);       // 8192 B
    int gb = b - NSB - 1;
    int node0 = gb * 64;
    #pragma unroll
    for (int i = 0; i < 4; ++i) {            // stage x tile (coalesced float4)
        int idx = i * 256 + t;
        int row = idx >> 4;
        int c4  = idx & 15;
        int gn  = node0 + row;
        int gr  = (gn < NN) ? gn : NN - 1;
        float4 f = *(const float4*)(x + gr * 64 + c4 * 4);
        unsigned lo = f2bf(f.x) | (f2bf(f.y) << 16);
        unsigned hi = f2bf(f.z) | (f2bf(f.w) << 16);
        *(uint2*)&xs[row][c4 * 4] = make_uint2(lo, hi);
    }
    for (int idx = t; idx < 4096; idx += 256) {  // self-pack W1 -> LDS
        int j = idx & 7;
        int n = (idx >> 3) & 15;
        int f = idx >> 7;
        int q = f & 3;
        int s = (f >> 2) & 1;
        int c = f >> 3;
        int kk = 32 * s + 8 * q + j;
        wpl[idx] = (unsigned short)f2bf(W1[kk * 64 + (16 * c + n)]);
    }
    __syncthreads();

    int lane = t & 63;
    int wv = t >> 6;
    int m = lane & 15, quad = lane >> 4;
    int nl = wv * 16 + m;

    Frag a[2];
    #pragma unroll
    for (int s = 0; s < 2; ++s)
        a[s].u = *(const uint4*)&xs[nl][s * 32 + quad * 8];
    Frag bf[8];
    #pragma unroll
    for (int cs = 0; cs < 8; ++cs)
        bf[cs].u = *(const uint4*)&wpl[((cs * 4 + quad) * 16 + m) * 8];

    v4f acc[4] = {};
    #pragma unroll
    for (int c = 0; c < 4; ++c) {
        acc[c] = __builtin_amdgcn_mfma_f32_16x16x32_bf16(a[0].v, bf[c * 2 + 0].v, acc[c], 0, 0, 0);
        acc[c] = __builtin_amdgcn_mfma_f32_16x16x32_bf16(a[1].v, bf[c * 2 + 1].v, acc[c], 0, 0, 0);
    }
    #pragma unroll
    for (int r = 0; r < 4; ++r) {
        int onode = node0 + wv * 16 + quad * 4 + r;
        #pragma unroll
        for (int c = 0; c < 4; ++c) {
            float v = acc[c][r];
            float p = __shfl_xor(v, 1);
            if (!(lane & 1)) {
                if (onode < NN)
                    outA[onode * 32 + c * 8 + (m >> 1)] = f2bf(v) | (f2bf(p) << 16);
                else if (onode == NN)
                    outA[onode * 32 + c * 8 + (m >> 1)] = 0u;   // zero row for padding
            }
        }
    }
}

// ---------------- K2: per-bucket scan of 512 chunk counts --------------------
// baseTT is CHUNK-MAJOR: baseTT[chunk * NBUCK + bucket].
__global__ void colscan_kernel(const int* __restrict__ histT, int* __restrict__ baseTT,
                               int* __restrict__ btot) {
    __shared__ int sd[256];
    int k = blockIdx.x, t = threadIdx.x;
    const int* col = histT + k * NSB;
    int a0 = col[2 * t], a1 = col[2 * t + 1];
    int my = a0 + a1;
    sd[t] = my;
    __syncthreads();
    #pragma unroll
    for (int off = 1; off < 256; off <<= 1) {
        int v = (t >= off) ? sd[t - off] : 0;
        __syncthreads();
        sd[t] += v;
        __syncthreads();
    }
    int excl = sd[t] - my;
    baseTT[(2 * t) * NBUCK + k]     = excl;
    baseTT[(2 * t + 1) * NBUCK + k] = excl + a0;
    if (t == 255) btot[k] = sd[255];
}

// ---------------- K3: 2-chunk bucket scatter ---------------------------------
__global__ void scatter_kernel(const int* __restrict__ src, const int* __restrict__ dst,
                               const int* __restrict__ baseTT, const int* __restrict__ btot,
                               int* __restrict__ pairs) {
    __shared__ int lcur[NBUCK];
    __shared__ int sd[256];
    int b = blockIdx.x, t = threadIdx.x;
    int base4 = t * 4;
    int d0 = (base4 + 0 < NBUCK) ? btot[base4 + 0] : 0;
    int d1 = (base4 + 1 < NBUCK) ? btot[base4 + 1] : 0;
    int d2 = (base4 + 2 < NBUCK) ? btot[base4 + 2] : 0;
    int d3 = (base4 + 3 < NBUCK) ? btot[base4 + 3] : 0;
    int my = d0 + d1 + d2 + d3;
    sd[t] = my;
    __syncthreads();
    #pragma unroll
    for (int off = 1; off < 256; off <<= 1) {
        int v = (t >= off) ? sd[t - off] : 0;
        __syncthreads();
        sd[t] += v;
        __syncthreads();
    }
    int excl = sd[t] - my;
    const int* bcol = baseTT + (b * SCHUNK) * NBUCK;   // contiguous column
    if (base4 + 0 < NBUCK) lcur[base4 + 0] = excl + bcol[base4 + 0];
    if (base4 + 1 < NBUCK) lcur[base4 + 1] = excl + d0 + bcol[base4 + 1];
    if (base4 + 2 < NBUCK) lcur[base4 + 2] = excl + d0 + d1 + bcol[base4 + 2];
    if (base4 + 3 < NBUCK) lcur[base4 + 3] = excl + d0 + d1 + d2 + bcol[base4 + 3];
    __syncthreads();
    int start = b * ESCB, end = start + ESCB;
    int e = start + t;
    for (; e + 3 * 256 < end; e += 4 * 256) {
        int dd0 = dst[e], dd1 = dst[e + 256], dd2 = dst[e + 512], dd3 = dst[e + 768];
        int ss0 = src[e], ss1 = src[e + 256], ss2 = src[e + 512], ss3 = src[e + 768];
        int p0 = atomicAdd(&lcur[dd0 >> 7], 1);
        int p1 = atomicAdd(&lcur[dd1 >> 7], 1);
        int p2 = atomicAdd(&lcur[dd2 >> 7], 1);
        int p3 = atomicAdd(&lcur[dd3 >> 7], 1);
        pairs[p0] = ((dd0 & 127) << 20) | ss0;
        pairs[p1] = ((dd1 & 127) << 20) | ss1;
        pairs[p2] = ((dd2 & 127) << 20) | ss2;
        pairs[p3] = ((dd3 & 127) << 20) | ss3;
    }
    for (; e < end; e += 256) {
        int d = dst[e];
        int pos = atomicAdd(&lcur[d >> 7], 1);
        pairs[pos] = ((d & 127) << 20) | src[e];
    }
}

// ---------------- K4: per-bucket padded CSR placement + dinv -----------------
__global__ void place_deg_kernel(const int* __restrict__ btot,
                                 const int* __restrict__ pairs,
                                 int2* __restrict__ rs_pd, float* __restrict__ dinv,
                                 int* __restrict__ srt) {
    __shared__ int lp[PCAP];
    __shared__ int lcnt[NPB];
    __shared__ int loff[NPB];
    __shared__ int lpos[NPB];
    __shared__ int sd[256];
    __shared__ int bs_s;
    int k = blockIdx.x, t = threadIdx.x;
    int node0 = k * NPB;
    int part = 0;
    for (int i = t; i < k; i += 256) part += btot[i];
    sd[t] = part;
    __syncthreads();
    #pragma unroll
    for (int off = 128; off; off >>= 1) {
        if (t < off) sd[t] += sd[t + off];
        __syncthreads();
    }
    if (t == 0) bs_s = sd[0];
    if (t < NPB) { lcnt[t] = 0; lpos[t] = 0; }
    if (k == 0 && t == 0) dinv[NN] = 0.f;   // dinv of the zero row (pads)
    __syncthreads();
    int bs = bs_s;
    int n = btot[k];
    int base = bs + k * BPAD;
    for (int pos = t; pos < n; pos += 256) {
        int p = pairs[bs + pos];
        if (pos < PCAP) lp[pos] = p;
        atomicAdd(&lcnt[p >> 20], 1);
    }
    __syncthreads();
    int my = (t < NPB) ? lcnt[t] : 0;
    int pd = (my + 7) & ~7;              // padded degree
    if (t < NPB) sd[t] = pd;
    __syncthreads();
    #pragma unroll
    for (int off = 1; off < NPB; off <<= 1) {
        int v = (t < NPB && t >= off) ? sd[t - off] : 0;
        __syncthreads();
        if (t < NPB) sd[t] += v;
        __syncthreads();
    }
    if (t < NPB) {
        int excl = sd[t] - pd;
        loff[t] = excl;
        int nd = node0 + t;
        if (nd < NN) {
            rs_pd[nd] = make_int2(base + excl, pd);
            dinv[nd] = rsqrtf((float)(my + 1));
            for (int kk = my; kk < pd; ++kk)
                srt[base + excl + kk] = NN;   // pad -> zero row
        }
    }
    __syncthreads();
    for (int pos = t; pos < n; pos += 256) {
        int p = (pos < PCAP) ? lp[pos] : pairs[bs + pos];
        int loc = p >> 20;
        int off = atomicAdd(&lpos[loc], 1);
        srt[base + loff[loc] + off] = p & 0xFFFFF;
    }
}

// ---------------- gather core A: prescaled rows, software-pipelined ----------
__device__ inline void gather8(const int2* __restrict__ rs_pd,
                               const int* __restrict__ srt,
                               const uint4* __restrict__ hb4,
                               int node, int q8, float a[8]) {
    int2 rp = rs_pd[node];
    uint4 u0 = hb4[node * 8 + q8];   // self-loop term
    a[0] = __uint_as_float(u0.x << 16);
    a[1] = __uint_as_float(u0.x & 0xffff0000u);
    a[2] = __uint_as_float(u0.y << 16);
    a[3] = __uint_as_float(u0.y & 0xffff0000u);
    a[4] = __uint_as_float(u0.z << 16);
    a[5] = __uint_as_float(u0.z & 0xffff0000u);
    a[6] = __uint_as_float(u0.w << 16);
    a[7] = __uint_as_float(u0.w & 0xffff0000u);
    int nch = rp.y >> 3;
    if (nch == 0) return;
    int base = rp.x + q8;
    int sc = srt[base];
    int i0 = BCAST8(sc, 0), i1 = BCAST8(sc, 1), i2 = BCAST8(sc, 2), i3 = BCAST8(sc, 3);
    int i4 = BCAST8(sc, 4), i5 = BCAST8(sc, 5), i6 = BCAST8(sc, 6), i7 = BCAST8(sc, 7);
    uint4 c0 = hb4[i0 * 8 + q8], c1 = hb4[i1 * 8 + q8];
    uint4 c2 = hb4[i2 * 8 + q8], c3 = hb4[i3 * 8 + q8];
    uint4 c4 = hb4[i4 * 8 + q8], c5 = hb4[i5 * 8 + q8];
    uint4 c6 = hb4[i6 * 8 + q8], c7 = hb4[i7 * 8 + q8];
    int sn = (nch > 1) ? srt[base + 8] : 0;
    #pragma unroll 2
    for (int i = 1; i < nch; ++i) {
        int j0 = BCAST8(sn, 0), j1 = BCAST8(sn, 1), j2 = BCAST8(sn, 2), j3 = BCAST8(sn, 3);
        int j4 = BCAST8(sn, 4), j5 = BCAST8(sn, 5), j6 = BCAST8(sn, 6), j7 = BCAST8(sn, 7);
        uint4 n0 = hb4[j0 * 8 + q8], n1 = hb4[j1 * 8 + q8];
        uint4 n2 = hb4[j2 * 8 + q8], n3 = hb4[j3 * 8 + q8];
        uint4 n4 = hb4[j4 * 8 + q8], n5 = hb4[j5 * 8 + q8];
        uint4 n6 = hb4[j6 * 8 + q8], n7 = hb4[j7 * 8 + q8];
        int sf = (i + 1 < nch) ? srt[base + (i + 1) * 8] : 0;
        ACC8(c0); ACC8(c1); ACC8(c2); ACC8(c3);
        ACC8(c4); ACC8(c5); ACC8(c6); ACC8(c7);
        c0 = n0; c1 = n1; c2 = n2; c3 = n3;
        c4 = n4; c5 = n5; c6 = n6; c7 = n7;
        sn = sf;
    }
    ACC8(c0); ACC8(c1); ACC8(c2); ACC8(c3);
    ACC8(c4); ACC8(c5); ACC8(c6); ACC8(c7);
}

// ---------------- gather core B: unscaled rows + dinv[src], pipelined --------
__device__ inline void gather8n(const int2* __restrict__ rs_pd,
                                const int* __restrict__ srt,
                                const uint4* __restrict__ hb4,
                                const float* __restrict__ dinv,
                                int node, int q8, float di, float a[8]) {
    int2 rp = rs_pd[node];
    uint4 u0 = hb4[node * 8 + q8];   // self-loop term (unscaled)
    a[0] = di * __uint_as_float(u0.x << 16);
    a[1] = di * __uint_as_float(u0.x & 0xffff0000u);
    a[2] = di * __uint_as_float(u0.y << 16);
    a[3] = di * __uint_as_float(u0.y & 0xffff0000u);
    a[4] = di * __uint_as_float(u0.z << 16);
    a[5] = di * __uint_as_float(u0.z & 0xffff0000u);
    a[6] = di * __uint_as_float(u0.w << 16);
    a[7] = di * __uint_as_float(u0.w & 0xffff0000u);
    int nch = rp.y >> 3;
    if (nch == 0) return;
    int base = rp.x + q8;
    int sc = srt[base];
    float dc = dinv[sc];             // dinv[NN] = 0 covers pads
    int i0 = BCAST8(sc, 0), i1 = BCAST8(sc, 1), i2 = BCAST8(sc, 2), i3 = BCAST8(sc, 3);
    int i4 = BCAST8(sc, 4), i5 = BCAST8(sc, 5), i6 = BCAST8(sc, 6), i7 = BCAST8(sc, 7);
    uint4 c0 = hb4[i0 * 8 + q8], c1 = hb4[i1 * 8 + q8];
    uint4 c2 = hb4[i2 * 8 + q8], c3 = hb4[i3 * 8 + q8];
    uint4 c4 = hb4[i4 * 8 + q8], c5 = hb4[i5 * 8 + q8];
    uint4 c6 = hb4[i6 * 8 + q8], c7 = hb4[i7 * 8 + q8];
    int sn = 0; float dn = 0.f;
    if (nch > 1) { sn = srt[base + 8]; dn = dinv[sn]; }
    #pragma unroll 2
    for (int i = 1; i < nch; ++i) {
        int j0 = BCAST8(sn, 0), j1 = BCAST8(sn, 1), j2 = BCAST8(sn, 2), j3 = BCAST8(sn, 3);
        int j4 = BCAST8(sn, 4), j5 = BCAST8(sn, 5), j6 = BCAST8(sn, 6), j7 = BCAST8(sn, 7);
        uint4 n0 = hb4[j0 * 8 + q8], n1 = hb4[j1 * 8 + q8];
        uint4 n2 = hb4[j2 * 8 + q8], n3 = hb4[j3 * 8 + q8];
        uint4 n4 = hb4[j4 * 8 + q8], n5 = hb4[j5 * 8 + q8];
        uint4 n6 = hb4[j6 * 8 + q8], n7 = hb4[j7 * 8 + q8];
        int sf = 0; float df = 0.f;
        if (i + 1 < nch) { sf = srt[base + (i + 1) * 8]; df = dinv[sf]; }
        int dci = __float_as_int(dc);
        float w0 = __int_as_float(BCAST8(dci, 0));
        float w1 = __int_as_float(BCAST8(dci, 1));
        float w2 = __int_as_float(BCAST8(dci, 2));
        float w3 = __int_as_float(BCAST8(dci, 3));
        float w4 = __int_as_float(BCAST8(dci, 4));
        float w5 = __int_as_float(BCAST8(dci, 5));
        float w6 = __int_as_float(BCAST8(dci, 6));
        float w7 = __int_as_float(BCAST8(dci, 7));
        ACC8N(c0, w0); ACC8N(c1, w1); ACC8N(c2, w2); ACC8N(c3, w3);
        ACC8N(c4, w4); ACC8N(c5, w5); ACC8N(c6, w6); ACC8N(c7, w7);
        c0 = n0; c1 = n1; c2 = n2; c3 = n3;
        c4 = n4; c5 = n5; c6 = n6; c7 = n7;
        dc = dn; sn = sf; dn = df;
    }
    int dci = __float_as_int(dc);
    float w0 = __int_as_float(BCAST8(dci, 0));
    float w1 = __int_as_float(BCAST8(dci, 1));
    float w2 = __int_as_float(BCAST8(dci, 2));
    float w3 = __int_as_float(BCAST8(dci, 3));
    float w4 = __int_as_float(BCAST8(dci, 4));
    float w5 = __int_as_float(BCAST8(dci, 5));
    float w6 = __int_as_float(BCAST8(dci, 6));
    float w7 = __int_as_float(BCAST8(dci, 7));
    ACC8N(c0, w0); ACC8N(c1, w1); ACC8N(c2, w2); ACC8N(c3, w3);
    ACC8N(c4, w4); ACC8N(c5, w5); ACC8N(c6, w6); ACC8N(c7, w7);
}

// ---------------- K5: layer-1 aggregate -> LDS -> layer-2 gemm (MFMA) --------
// launch_bounds(256,4): cap VGPR at ~128 so the gather double-buffer stays
// genuinely live (VGPR 56 in r8 = pipeline squashed) while keeping >=16 waves/CU.
__global__ void __launch_bounds__(256, 4)
agg1_gemm2_kernel(const int2* __restrict__ rs_pd,
                  const int* __restrict__ srt,
                  const uint4* __restrict__ hb4,   // bufA (unscaled)
                  const float* __restrict__ dinv,
                  const float* __restrict__ b1,
                  const unsigned short* __restrict__ Wp2,
                  unsigned* __restrict__ out /* bufC bf16 rows */) {
    __shared__ unsigned short hsl[64][80];
    int t = threadIdx.x;
    int lane = t & 63, wv = t >> 6;
    int node0 = blockIdx.x * 64;
    int q8 = lane & 7, g = lane >> 3;
    float4 bb0 = *(const float4*)(b1 + q8 * 8);
    float4 bb1 = *(const float4*)(b1 + q8 * 8 + 4);

    #pragma unroll
    for (int pass = 0; pass < 2; ++pass) {
        int nl = wv * 16 + pass * 8 + g;
        int node = node0 + nl;
        int cn = (node < NN) ? node : NN - 1;
        float di = dinv[cn];
        float a[8];
        gather8n(rs_pd, srt, hb4, dinv, cn, q8, di, a);
        a[0] = fmaxf(fmaf(di, a[0], bb0.x), 0.f);
        a[1] = fmaxf(fmaf(di, a[1], bb0.y), 0.f);
        a[2] = fmaxf(fmaf(di, a[2], bb0.z), 0.f);
        a[3] = fmaxf(fmaf(di, a[3], bb0.w), 0.f);
        a[4] = fmaxf(fmaf(di, a[4], bb1.x), 0.f);
        a[5] = fmaxf(fmaf(di, a[5], bb1.y), 0.f);
        a[6] = fmaxf(fmaf(di, a[6], bb1.z), 0.f);
        a[7] = fmaxf(fmaf(di, a[7], bb1.w), 0.f);
        uint4 pk;
        pk.x = f2bf(a[0]) | (f2bf(a[1]) << 16);
        pk.y = f2bf(a[2]) | (f2bf(a[3]) << 16);
        pk.z = f2bf(a[4]) | (f2bf(a[5]) << 16);
        pk.w = f2bf(a[6]) | (f2bf(a[7]) << 16);
        *(uint4*)&hsl[nl][q8 * 8] = pk;
    }
    __syncthreads();

    int m = lane & 15, quad = lane >> 4;
    Frag b[8];
    #pragma unroll
    for (int cs = 0; cs < 8; ++cs)
        b[cs].u = *(const uint4*)(Wp2 + ((cs * 4 + quad) * 16 + m) * 8);
    Frag a2[2];
    #pragma unroll
    for (int s = 0; s < 2; ++s)
        a2[s].u = *(const uint4*)&hsl[wv * 16 + m][s * 32 + quad * 8];

    v4f acc[4] = {};
    #pragma unroll
    for (int c = 0; c < 4; ++c) {
        acc[c] = __builtin_amdgcn_mfma_f32_16x16x32_bf16(a2[0].v, b[c * 2 + 0].v, acc[c], 0, 0, 0);
        acc[c] = __builtin_amdgcn_mfma_f32_16x16x32_bf16(a2[1].v, b[c * 2 + 1].v, acc[c], 0, 0, 0);
    }
    // bufC rows are PRE-scaled by dinv[onode] (layer-2 gather uses gather8)
    #pragma unroll
    for (int r = 0; r < 4; ++r) {
        int onode = node0 + wv * 16 + quad * 4 + r;
        float di = dinv[(onode < NN) ? onode : NN - 1];
        #pragma unroll
        for (int c = 0; c < 4; ++c) {
            float v = acc[c][r] * di;
            float p = __shfl_xor(v, 1);
            if (!(lane & 1)) {
                if (onode < NN)
                    out[onode * 32 + c * 8 + (m >> 1)] = f2bf(v) | (f2bf(p) << 16);
                else if (onode == NN)
                    out[onode * 32 + c * 8 + (m >> 1)] = 0u;   // zero row for padding
            }
        }
    }
}

// ---------------- K6: layer-2 aggregate fused with FC + log_softmax ----------
__global__ void __launch_bounds__(256, 4)
aggregate2_final_kernel(const int2* __restrict__ rs_pd,
                        const int* __restrict__ srt,
                        const uint4* __restrict__ hb4,  // bufC
                        const float* __restrict__ dinv,
                        const float* __restrict__ b2,
                        const float* __restrict__ Wfc,
                        const float* __restrict__ bfc,
                        float* __restrict__ out) {
    __shared__ float Ws[64][16];
    __shared__ float hs[32][68];
    int t = threadIdx.x;
    #pragma unroll
    for (int k = 0; k < 4; ++k)
        ((float*)Ws)[k * 256 + t] = Wfc[k * 256 + t];

    int nl = t >> 3, q8 = t & 7;
    int node = blockIdx.x * 32 + nl;      // NN = 3125 * 32 exactly
    float a[8];
    gather8(rs_pd, srt, hb4, node, q8, a);
    float di = dinv[node];
    float4 bb0 = *(const float4*)(b2 + q8 * 8);
    float4 bb1 = *(const float4*)(b2 + q8 * 8 + 4);
    float4 r0, r1;
    r0.x = fmaxf(fmaf(di, a[0], bb0.x), 0.f);
    r0.y = fmaxf(fmaf(di, a[1], bb0.y), 0.f);
    r0.z = fmaxf(fmaf(di, a[2], bb0.z), 0.f);
    r0.w = fmaxf(fmaf(di, a[3], bb0.w), 0.f);
    r1.x = fmaxf(fmaf(di, a[4], bb1.x), 0.f);
    r1.y = fmaxf(fmaf(di, a[5], bb1.y), 0.f);
    r1.z = fmaxf(fmaf(di, a[6], bb1.z), 0.f);
    r1.w = fmaxf(fmaf(di, a[7], bb1.w), 0.f);
    *(float4*)&hs[nl][q8 * 8]     = r0;
    *(float4*)&hs[nl][q8 * 8 + 4] = r1;
    __syncthreads();

    #pragma unroll
    for (int it = 0; it < 2; ++it) {
        int idx = it * 256 + t;
        int n2 = idx >> 4;
        int c  = idx & 15;
        float acc = bfc[c];
        #pragma unroll
        for (int k = 0; k < 64; ++k)
            acc = fmaf(hs[n2][k], Ws[k][c], acc);
        float mx = acc;
        #pragma unroll
        for (int off = 8; off; off >>= 1)
            mx = fmaxf(mx, __shfl_xor(mx, off, 16));
        float ex = __expf(acc - mx);
        float s = ex;
        #pragma unroll
        for (int off = 8; off; off >>= 1)
            s += __shfl_xor(s, off, 16);
        out[blockIdx.x * 512 + idx] = acc - mx - __logf(s);
    }
}

extern "C" void kernel_launch(void* const* d_in, const int* in_sizes, int n_in,
                              void* d_out, int out_size, void* d_ws, size_t ws_size,
                              hipStream_t stream) {
    const float* x   = (const float*)d_in[0];
    const int*   ei  = (const int*)d_in[1];     // [2, E] int32
    const float* W1  = (const float*)d_in[2];
    const float* b1  = (const float*)d_in[3];
    const float* W2  = (const float*)d_in[4];
    const float* b2  = (const float*)d_in[5];
    const float* Wfc = (const float*)d_in[6];
    const float* bfc = (const float*)d_in[7];
    float* out = (float*)d_out;

    char* ws = (char*)d_ws;
    int2*     rs_pd  = (int2*)(ws + 0);             //  800,000 B
    float*    dinv   = (float*)(ws + 800000);       //  (NN+1)*4 -> ends 1200004
    int*      btot   = (int*)(ws + 1200128);        //  3128 B
    int*      histT  = (int*)(ws + 1203328);        //  1,601,536 -> ends 2804864
    int*      baseTT = (int*)(ws + 2804864);        //  1,601,536 -> ends 4406400 (chunk-major)
    int*      srt    = (int*)(ws + 4406400);        //  9,202,688 -> ends 13609088
    unsigned* bufA   = (unsigned*)(ws + 13609088);  // 12,800,128 -> ends 26409216
    int*      pairs  = (int*)(ws + 26409216);       //  6.4 MB (dead after K4)
    unsigned* bufC   = (unsigned*)(ws + 26409216);  // 12,800,128, overlays pairs -> ends 39209344
    unsigned short* Wp2 = (unsigned short*)(ws + 39209344);  // 8 KB -> ends 39217536

    const int* src = ei;        // edge_index[0]
    const int* dst = ei + NE;   // edge_index[1]

    // K1: histogram + wpack W2 + layer-1 GEMM (independent halves, one dispatch)
    hist_wpack_gemm_kernel<<<NSB + 1 + GEMMB, 256, 0, stream>>>(dst, histT, W1, W2,
                                                                Wp2, x, bufA);
    // K2: per-bucket column scan (chunk-major output)
    colscan_kernel<<<NBUCK, 256, 0, stream>>>(histT, baseTT, btot);
    // K3: bucket scatter
    scatter_kernel<<<SCATB, 256, 0, stream>>>(src, dst, baseTT, btot, pairs);
    // K4: padded CSR placement + deg/dinv
    place_deg_kernel<<<NBUCK, 256, 0, stream>>>(btot, pairs, rs_pd, dinv, srt);
    // K5: layer-1 aggregate (dinv at gather, pipelined) + layer-2 gemm
    agg1_gemm2_kernel<<<(NN + 63) / 64, 256, 0, stream>>>(rs_pd, srt,
        (const uint4*)bufA, dinv, b1, Wp2, bufC);
    // K6: layer-2 aggregate (pipelined) + FC + log_softmax
    aggregate2_final_kernel<<<NN / 32, 256, 0, stream>>>(rs_pd, srt,
        (const uint4*)bufC, dinv, b2, Wfc, bfc, out);
}